// Round 4
// baseline (250.144 us; speedup 1.0000x reference)
//
#include <hip/hip_runtime.h>

typedef __attribute__((ext_vector_type(8))) short short8;
typedef __attribute__((ext_vector_type(4))) float float4f;
typedef __attribute__((ext_vector_type(4))) unsigned short ushort4v;

#define PITCH 136   // shorts/row in LDS planes
#define LOG_SLOPE -2.302585092994046f   // log(0.1)
#define LN2 0.6931471805599453f
#define NBLK 268    // 12 LU + 256 fwd (16 rows per fwd block, single wave)
#define LDS_BYTES 32256   // 6 planes * 16*136*2 + 1536 bias floats
// ws layout (floats): [0] ticket | [2..13] logdet partials | [64..4159] counts
// [4160..5695] fp32 biases | [8192..] W hi/lo ushort planes
#define WS_BIAS 4160
#define WS_WPLANES 8192
#define NWELEM 196608   // 12 * 16384

__device__ __forceinline__ float bf2f(unsigned int u) {
    return __builtin_bit_cast(float, u << 16);
}
__device__ __forceinline__ unsigned short f2bf(float f) {
    unsigned int x = __builtin_bit_cast(unsigned int, f);
    x += 0x7fff + ((x >> 16) & 1);   // round-to-nearest-even
    return (unsigned short)(x >> 16);
}
__device__ __forceinline__ float4f vmsub(float4f a, float s, float4f b) {
    a[0] -= s * b[0]; a[1] -= s * b[1]; a[2] -= s * b[2]; a[3] -= s * b[3];
    return a;
}

template<int ISF32>
__device__ __forceinline__ float ldv(const void* p, int i) {
    if (ISF32) return ((const float*)p)[i];
    return bf2f(((const unsigned short*)p)[i]);
}

// Per-wave dtype sniff: fp32 weights read as u16 pairs have uniform-random
// mantissa halves; bf16 weights have exponent fields in a narrow band.
__device__ __forceinline__ int detect_f32(const unsigned short* W1u, int lane) {
    unsigned int u = W1u[lane * 2];
    unsigned int e = (u >> 7) & 0xFF;
    int bad = (e < 64) || (e > 135);
    return __ballot(bad) != 0ull;
}

__device__ __forceinline__ float4f mfma16(short8 a, short8 b, float4f c) {
    return __builtin_amdgcn_mfma_f32_16x16x32_bf16(a, b, c, 0, 0, 0);
}

__device__ __forceinline__ void split8(float4f a, float4f b, short8& hi, short8& lo) {
#pragma unroll
    for (int j = 0; j < 4; ++j) {
        float v = a[j]; unsigned short h = f2bf(v);
        hi[j] = (short)h; lo[j] = (short)f2bf(v - bf2f(h));
        v = b[j]; h = f2bf(v);
        hi[4 + j] = (short)h; lo[4 + j] = (short)f2bf(v - bf2f(h));
    }
}

// ---- prep: W -> bf16 hi/lo planes, biases -> fp32, zero ticket ----
__global__ void k_prep(const void* __restrict__ W1, const void* __restrict__ W2,
                       const void* __restrict__ W3, const void* __restrict__ b1,
                       const void* __restrict__ b2, const void* __restrict__ b3,
                       float* __restrict__ ws) {
    const int tid = threadIdx.x, bid = blockIdx.x;
    const int isf32 = detect_f32((const unsigned short*)W1, tid & 63);
    unsigned short* whi = (unsigned short*)(ws + WS_WPLANES);
    unsigned short* wlo = whi + NWELEM;
    if (bid < 96) {
        int s = (bid * 256 + tid) * 8;        // 96*256*8 = 196608
        int mat = s >> 14, off = s & 16383;   // mat = wsel*4 + layer
        int wsel = mat >> 2;
        const void* Wm = wsel == 0 ? W1 : (wsel == 1 ? W2 : W3);
        int src = (mat & 3) * 16384 + off;
        short8 hi, lo;
        if (isf32) {
            const float* p = (const float*)Wm + src;
            split8(*(const float4f*)p, *(const float4f*)(p + 4), hi, lo);
        } else {
            hi = *(const short8*)((const unsigned short*)Wm + src);
            lo = (short8){0, 0, 0, 0, 0, 0, 0, 0};
        }
        *(short8*)(whi + s) = hi;
        *(short8*)(wlo + s) = lo;
    } else {
        for (int e = tid; e < 1536; e += 256) {
            int bsel = e >> 9, idx = e & 511;
            const void* bp = bsel == 0 ? b1 : (bsel == 1 ? b2 : b3);
            ws[WS_BIAS + e] = isf32 ? ((const float*)bp)[idx]
                                    : bf2f(((const unsigned short*)bp)[idx]);
        }
        if (tid == 0) ((int*)ws)[0] = 0;   // finalize ticket
    }
}

// One 16-col weight tile as a VALUE struct (round-0 codegen idiom: by-value /
// const-ref aggregates promote to VGPRs; pointer-passed arrays went to scratch
// in r1-r3 -- 13MB scratch traffic, VGPR pegged at 256).
// fp32: hi+lo interleaved (8 short8 = 32 VGPR); bf16: hi only (4 short8 = 16 VGPR,
// weight lo planes are exactly zero so skipping them is bit-identical).
template<int ISF32> struct WT { short8 v[ISF32 ? 8 : 4]; };
struct XF { short8 h[4], l[4]; };

template<int ISF32>
__device__ __forceinline__ WT<ISF32> loadTile(const unsigned short* __restrict__ wh,
                                              const unsigned short* __restrict__ wl,
                                              int ct, int m, int q) {
    WT<ISF32> r;
    const unsigned short* ph = wh + (ct * 16 + m) * 128 + q * 8;
#pragma unroll
    for (int kk = 0; kk < 4; ++kk)
        r.v[kk * (ISF32 ? 2 : 1)] = *(const short8*)(ph + kk * 32);
    if (ISF32) {
        const unsigned short* pl = wl + (ct * 16 + m) * 128 + q * 8;
#pragma unroll
        for (int kk = 0; kk < 4; ++kk)
            r.v[kk * 2 + 1] = *(const short8*)(pl + kk * 32);
    }
    return r;
}

template<int ISF32>
__device__ __forceinline__ float4f dotTile(const WT<ISF32>& w, const XF& x, float4f acc) {
#pragma unroll
    for (int kk = 0; kk < 4; ++kk) {
        if (ISF32) {
            acc = mfma16(x.h[kk], w.v[kk * 2 + 0], acc);
            acc = mfma16(x.l[kk], w.v[kk * 2 + 0], acc);
            acc = mfma16(x.h[kk], w.v[kk * 2 + 1], acc);
        } else {
            acc = mfma16(x.h[kk], w.v[kk], acc);
            acc = mfma16(x.l[kk], w.v[kk], acc);
        }
    }
    return acc;
}

// Single-wave matvec: out[16x128] = f(in[16x128] @ W^T + bias). No barriers:
// same-wave LDS ordering suffices. s0/s1/s2 are rolling value-struct slots.
// Entry invariant: (s0,s1,s2) = tiles (0,1,2) of CURRENT matrix.
// Exit invariant:  (s0,s1,s2) = tiles (0,1,2) of NEXT matrix.
// Schedule: consume tile t from slot t%3, reload that slot immediately; the
// reload's L2 latency is covered by the next two dotTiles (24 MFMA) and, for
// the next-matrix tiles, by the epilogue + next matvec's x-fragment loads.
// MODE 0: out=leaky(v) | 1: v+=res(LDS,=out plane), write | 2: leaky+count | 3: count only
template<int MODE, int ISF32>
__device__ __forceinline__ void matvec(
        WT<ISF32>& s0, WT<ISF32>& s1, WT<ISF32>& s2,
        const unsigned short* __restrict__ inh, const unsigned short* __restrict__ inl,
        unsigned short* outh, unsigned short* outl,
        const unsigned short* __restrict__ cwh, const unsigned short* __restrict__ cwl,
        const unsigned short* __restrict__ nwh, const unsigned short* __restrict__ nwl,
        const float* __restrict__ bias,
        int* cnt, int m, int q) {
    XF x;
#pragma unroll
    for (int kk = 0; kk < 4; ++kk) {
        x.h[kk] = *(const short8*)(inh + m * PITCH + kk * 32 + q * 8);
        x.l[kk] = *(const short8*)(inl + m * PITCH + kk * 32 + q * 8);
    }
    float4f a0, a1, a2, a3, a4, a5, a6, a7;
    {
        float b;
        b = bias[0 * 16 + m]; a0 = (float4f){b, b, b, b};
        b = bias[1 * 16 + m]; a1 = (float4f){b, b, b, b};
        b = bias[2 * 16 + m]; a2 = (float4f){b, b, b, b};
        b = bias[3 * 16 + m]; a3 = (float4f){b, b, b, b};
        b = bias[4 * 16 + m]; a4 = (float4f){b, b, b, b};
        b = bias[5 * 16 + m]; a5 = (float4f){b, b, b, b};
        b = bias[6 * 16 + m]; a6 = (float4f){b, b, b, b};
        b = bias[7 * 16 + m]; a7 = (float4f){b, b, b, b};
    }
    a0 = dotTile<ISF32>(s0, x, a0); s0 = loadTile<ISF32>(cwh, cwl, 3, m, q);
    a1 = dotTile<ISF32>(s1, x, a1); s1 = loadTile<ISF32>(cwh, cwl, 4, m, q);
    a2 = dotTile<ISF32>(s2, x, a2); s2 = loadTile<ISF32>(cwh, cwl, 5, m, q);
    a3 = dotTile<ISF32>(s0, x, a3); s0 = loadTile<ISF32>(cwh, cwl, 6, m, q);
    a4 = dotTile<ISF32>(s1, x, a4); s1 = loadTile<ISF32>(cwh, cwl, 7, m, q);
    a5 = dotTile<ISF32>(s2, x, a5); s2 = loadTile<ISF32>(nwh, nwl, 2, m, q);
    a6 = dotTile<ISF32>(s0, x, a6); s0 = loadTile<ISF32>(nwh, nwl, 0, m, q);
    a7 = dotTile<ISF32>(s1, x, a7); s1 = loadTile<ISF32>(nwh, nwl, 1, m, q);

    // epilogue (C layout: row = q*4+r, col = ct*16+m), all indices literal
#define EPI_CT(A, CT)                                                          \
    {                                                                          \
        _Pragma("unroll")                                                      \
        for (int r = 0; r < 4; ++r) {                                          \
            float v = A[r];                                                    \
            const int o = (q * 4 + r) * PITCH + CT * 16 + m;                   \
            if (MODE == 1) v += bf2f(outh[o]) + bf2f(outl[o]);                 \
            if (MODE >= 2) cnt[r] += (v <= 0.0f) ? 1 : 0;                      \
            if (MODE == 0 || MODE == 2) v = v > 0.0f ? v : 0.1f * v;           \
            if (MODE != 3) {                                                   \
                unsigned short h = f2bf(v);                                    \
                outh[o] = h;                                                   \
                outl[o] = f2bf(v - bf2f(h));                                   \
            }                                                                  \
        }                                                                      \
    }
    EPI_CT(a0, 0) EPI_CT(a1, 1) EPI_CT(a2, 2) EPI_CT(a3, 3)
    EPI_CT(a4, 4) EPI_CT(a5, 5) EPI_CT(a6, 6) EPI_CT(a7, 7)
#undef EPI_CT
}

// Per-wave fwd: 16 rows through 4 layers x 5 matvecs, zero barriers.
// Planes: P0 = x/residual, P1/P2 = temporaries.
template<int ISF32>
__device__ void fwd(int bid, int lane, char* ldsb,
                    const void* __restrict__ x, const float* __restrict__ ws,
                    void* __restrict__ out, float* __restrict__ wsw) {
    unsigned short* P = (unsigned short*)ldsb;
    unsigned short* P0h = P + 0 * 16 * PITCH;
    unsigned short* P0l = P + 1 * 16 * PITCH;
    unsigned short* P1h = P + 2 * 16 * PITCH;
    unsigned short* P1l = P + 3 * 16 * PITCH;
    unsigned short* P2h = P + 4 * 16 * PITCH;
    unsigned short* P2l = P + 5 * 16 * PITCH;
    float* biasL = (float*)(ldsb + 6 * 16 * PITCH * 2);   // 1536 floats
    const unsigned short* whi = (const unsigned short*)(ws + WS_WPLANES);
    const unsigned short* wlo = whi + NWELEM;
    const float* biasG = ws + WS_BIAS;
    const int r0 = bid * 16;
    const int m = lane & 15, q = lane >> 4;

    // prologue: layer-0 w1 tiles 0..2 -> slots (loads fly while staging x + biases)
    WT<ISF32> s0 = loadTile<ISF32>(whi, wlo, 0, m, q);
    WT<ISF32> s1 = loadTile<ISF32>(whi, wlo, 1, m, q);
    WT<ISF32> s2 = loadTile<ISF32>(whi, wlo, 2, m, q);

    // stage biases -> LDS (read 8x per matvec as cheap ds_read_b32)
#pragma unroll
    for (int e = lane; e < 384; e += 64)
        *(float4f*)&biasL[e * 4] = *(const float4f*)&biasG[e * 4];

    // stage x -> P0 hi/lo (vectorized)
    if (ISF32) {
#pragma unroll
        for (int e = lane; e < 512; e += 64) {
            int r = e >> 5, c = (e & 31) * 4;
            float4f v = *(const float4f*)((const float*)x + (r0 + r) * 128 + c);
            ushort4v h, l;
#pragma unroll
            for (int j = 0; j < 4; ++j) {
                unsigned short hh = f2bf(v[j]);
                h[j] = hh; l[j] = f2bf(v[j] - bf2f(hh));
            }
            *(ushort4v*)(P0h + r * PITCH + c) = h;
            *(ushort4v*)(P0l + r * PITCH + c) = l;
        }
    } else {
        const short8 z = {0, 0, 0, 0, 0, 0, 0, 0};
#pragma unroll
        for (int e = lane; e < 256; e += 64) {
            int r = e >> 4, c = (e & 15) * 8;
            short8 v = *(const short8*)((const unsigned short*)x + (r0 + r) * 128 + c);
            *(short8*)(P0h + r * PITCH + c) = v;
            *(short8*)(P0l + r * PITCH + c) = z;
        }
    }
    int cnt[4] = {0, 0, 0, 0};
#pragma unroll 1
    for (int layer = 0; layer < 4; ++layer) {
        const unsigned short* w1h = whi + (0 + layer) * 16384;
        const unsigned short* w1l = wlo + (0 + layer) * 16384;
        const unsigned short* w2h = whi + (4 + layer) * 16384;
        const unsigned short* w2l = wlo + (4 + layer) * 16384;
        const unsigned short* w3h = whi + (8 + layer) * 16384;
        const unsigned short* w3l = wlo + (8 + layer) * 16384;
        const unsigned short* n1h = whi + ((layer + 1) & 3) * 16384;
        const unsigned short* n1l = wlo + ((layer + 1) & 3) * 16384;
        const float* b1p = biasL + layer * 128;
        const float* b2p = biasL + 512 + layer * 128;
        const float* b3p = biasL + 1024 + layer * 128;
        matvec<0, ISF32>(s0, s1, s2, P0h, P0l, P1h, P1l, w1h, w1l, w2h, w2l, b1p, cnt, m, q);
        matvec<0, ISF32>(s0, s1, s2, P1h, P1l, P2h, P2l, w2h, w2l, w3h, w3l, b2p, cnt, m, q);
        matvec<1, ISF32>(s0, s1, s2, P2h, P2l, P0h, P0l, w3h, w3l, w1h, w1l, b3p, cnt, m, q);
        matvec<2, ISF32>(s0, s1, s2, P0h, P0l, P1h, P1l, w1h, w1l, w2h, w2l, b1p, cnt, m, q);
        matvec<3, ISF32>(s0, s1, s2, P1h, P1l, P1h, P1l, w2h, w2l, n1h, n1l, b2p, cnt, m, q);
    }
    // count reduction across the 16-lane col groups (rows q*4+r)
#pragma unroll
    for (int r = 0; r < 4; ++r) {
        int c = cnt[r];
        c += __shfl_xor(c, 1);
        c += __shfl_xor(c, 2);
        c += __shfl_xor(c, 4);
        c += __shfl_xor(c, 8);
        if (m == 0) wsw[64 + r0 + q * 4 + r] = (float)c;
    }
    // final x from P0 hi/lo (vectorized)
    if (ISF32) {
#pragma unroll
        for (int e = lane; e < 512; e += 64) {
            int r = e >> 5, c = (e & 31) * 4;
            ushort4v h = *(const ushort4v*)(P0h + r * PITCH + c);
            ushort4v l = *(const ushort4v*)(P0l + r * PITCH + c);
            float4f v;
#pragma unroll
            for (int j = 0; j < 4; ++j) v[j] = bf2f(h[j]) + bf2f(l[j]);
            *(float4f*)((float*)out + (r0 + r) * 128 + c) = v;
        }
    } else {
#pragma unroll
        for (int e = lane; e < 256; e += 64) {
            int r = e >> 4, c = (e & 15) * 8;
            short8 h = *(const short8*)(P0h + r * PITCH + c);
            short8 l = *(const short8*)(P0l + r * PITCH + c);
            short8 o;
#pragma unroll
            for (int j = 0; j < 8; ++j)
                o[j] = (short)f2bf(bf2f((unsigned short)h[j]) + bf2f((unsigned short)l[j]));
            *(short8*)((unsigned short*)out + (r0 + r) * 128 + c) = o;
        }
    }
}

// ---- register-resident unpivoted LU, RANK-4 per barrier (32 intervals).
template<int ISF32>
__device__ __forceinline__ float lu_logdet(int id, int tid, float* lds,
        const void* W1, const void* W2, const void* W3) {
    const int wsel = id % 3;
    const void* Wm = (wsel == 0 ? W1 : (wsel == 1 ? W2 : W3));
    const int ofs = (id / 3) * 16384;
    const int tx = tid & 31, ty = tid >> 5;
    float* rowbuf = lds;          // [2][4][128]: rows K..K+3
    float* colbuf = lds + 1024;   // [2][4][128]: cols K..K+3 packed [j][ty*16+m]
    float4f V[16];                // A[ty+8m][4tx..4tx+3]
#pragma unroll
    for (int m = 0; m < 16; ++m) {
        int base = ofs + (ty + 8 * m) * 128 + 4 * tx;
        if (ISF32) {
            V[m] = *(const float4f*)((const float*)Wm + base);
        } else {
            ushort4 u = *(const ushort4*)((const unsigned short*)Wm + base);
            V[m] = (float4f){bf2f(u.x), bf2f(u.y), bf2f(u.z), bf2f(u.w)};
        }
    }
    if (ty < 4) *(float4f*)&rowbuf[ty * 128 + 4 * tx] = V[0];
    if (tx == 0) {
#pragma unroll
        for (int j = 0; j < 4; ++j) {
#pragma unroll
            for (int mg = 0; mg < 4; ++mg) {
                float4f t = {V[mg * 4 + 0][j], V[mg * 4 + 1][j],
                             V[mg * 4 + 2][j], V[mg * 4 + 3][j]};
                *(float4f*)&colbuf[j * 128 + ty * 16 + mg * 4] = t;
            }
        }
    }
    __syncthreads();
    float logacc = 0.0f;
#pragma unroll 1
    for (int kap = 0; kap < 32; ++kap) {
        const int K = kap * 4;
        const int buf = (kap & 1) * 512;
        float4f D[4], R[4], C[4][4];
#pragma unroll
        for (int j = 0; j < 4; ++j) {
            D[j] = *(const float4f*)&rowbuf[buf + j * 128 + K];       // broadcast
            R[j] = *(const float4f*)&rowbuf[buf + j * 128 + 4 * tx];
#pragma unroll
            for (int mg = 0; mg < 4; ++mg)
                C[j][mg] = *(const float4f*)&colbuf[buf + j * 128 + ty * 16 + mg * 4];
        }
        float p0 = D[0][0], i0 = 1.0f / p0;
        float l10 = D[1][0] * i0, l20 = D[2][0] * i0, l30 = D[3][0] * i0;
        D[1] = vmsub(D[1], l10, D[0]); R[1] = vmsub(R[1], l10, R[0]);
        D[2] = vmsub(D[2], l20, D[0]); R[2] = vmsub(R[2], l20, R[0]);
        D[3] = vmsub(D[3], l30, D[0]); R[3] = vmsub(R[3], l30, R[0]);
        float p1 = D[1][1], i1 = 1.0f / p1;
        float l21 = D[2][1] * i1, l31 = D[3][1] * i1;
        D[2] = vmsub(D[2], l21, D[1]); R[2] = vmsub(R[2], l21, R[1]);
        D[3] = vmsub(D[3], l31, D[1]); R[3] = vmsub(R[3], l31, R[1]);
        float p2 = D[2][2], i2 = 1.0f / p2;
        float l32 = D[3][2] * i2;
        D[3] = vmsub(D[3], l32, D[2]); R[3] = vmsub(R[3], l32, R[2]);
        float p3 = D[3][3], i3 = 1.0f / p3;
        logacc += __log2f(fabsf(p0)) + __log2f(fabsf(p1))
                + __log2f(fabsf(p2)) + __log2f(fabsf(p3));
        float iv[4] = {i0, i1, i2, i3};
#pragma unroll
        for (int i = 0; i < 4; ++i) {
#pragma unroll
            for (int mg = 0; mg < 4; ++mg) {
#pragma unroll
                for (int e = 0; e < 4; ++e) {
                    int r = ty + 32 * mg + 8 * e;
                    C[i][mg][e] = (r > K + i) ? C[i][mg][e] * iv[i] : 0.0f;
                }
            }
#pragma unroll
            for (int j = i + 1; j < 4; ++j) {
                float uij = D[i][j];
#pragma unroll
                for (int mg = 0; mg < 4; ++mg)
                    C[j][mg] = vmsub(C[j][mg], uij, C[i][mg]);
            }
        }
#pragma unroll
        for (int mg = 0; mg < 4; ++mg) {
#pragma unroll
            for (int e = 0; e < 4; ++e) {
                float4f v = V[mg * 4 + e];
                v = vmsub(v, C[0][mg][e], R[0]);
                v = vmsub(v, C[1][mg][e], R[1]);
                v = vmsub(v, C[2][mg][e], R[2]);
                v = vmsub(v, C[3][mg][e], R[3]);
                V[mg * 4 + e] = v;
            }
        }
        if (kap < 31) {
            const int nbuf = ((kap + 1) & 1) * 512;
            const int tb = (kap & 1) ? 0 : 4;
            const int mn = (kap + 1) >> 1;
            if (ty >= tb && ty < tb + 4) {
                float4f val;
                switch (mn) {
                case 0:  val = V[0];  break; case 1:  val = V[1];  break;
                case 2:  val = V[2];  break; case 3:  val = V[3];  break;
                case 4:  val = V[4];  break; case 5:  val = V[5];  break;
                case 6:  val = V[6];  break; case 7:  val = V[7];  break;
                case 8:  val = V[8];  break; case 9:  val = V[9];  break;
                case 10: val = V[10]; break; case 11: val = V[11]; break;
                case 12: val = V[12]; break; case 13: val = V[13]; break;
                case 14: val = V[14]; break; default: val = V[15]; break;
                }
                *(float4f*)&rowbuf[nbuf + (ty - tb) * 128 + 4 * tx] = val;
            }
            if (tx == kap + 1) {
#pragma unroll
                for (int j = 0; j < 4; ++j) {
#pragma unroll
                    for (int mg = 0; mg < 4; ++mg) {
                        float4f t = {V[mg * 4 + 0][j], V[mg * 4 + 1][j],
                                     V[mg * 4 + 2][j], V[mg * 4 + 3][j]};
                        *(float4f*)&colbuf[nbuf + j * 128 + ty * 16 + mg * 4] = t;
                    }
                }
            }
        }
        __syncthreads();
    }
    return logacc * LN2;
}

__global__ __launch_bounds__(256, 1) void k_main(
        const void* __restrict__ x,
        const void* __restrict__ W1, const void* __restrict__ b1,
        const void* __restrict__ W2, const void* __restrict__ b2,
        const void* __restrict__ W3, const void* __restrict__ b3,
        void* __restrict__ out, float* __restrict__ ws) {
    extern __shared__ __align__(16) char ldsb[];
    const int tid = threadIdx.x;
    const int lane = tid & 63;
    // fwd blocks: single active wave, waves 1-3 exit before any barrier
    if (blockIdx.x >= 12 && tid >= 64) return;
    const int isf32 = detect_f32((const unsigned short*)W1, lane);

    if (blockIdx.x < 12) {
        float ld = isf32 ? lu_logdet<1>(blockIdx.x, tid, (float*)ldsb, W1, W2, W3)
                         : lu_logdet<0>(blockIdx.x, tid, (float*)ldsb, W1, W2, W3);
        if (tid == 0) ws[2 + blockIdx.x] = ld;
        if (tid >= 64) return;   // only wave 0 continues (no more barriers)
    } else {
        const int bid = blockIdx.x - 12;
        if (isf32) fwd<1>(bid, lane, ldsb, x, ws, out, ws);
        else       fwd<0>(bid, lane, ldsb, x, ws, out, ws);
    }

    // ---- last-block finalize (wave 0 only, wave-level broadcast) ----
    __threadfence();
    int lastf = 0;
    if (lane == 0) lastf = (atomicAdd((int*)ws, 1) == NBLK - 1) ? 1 : 0;
    lastf = __shfl(lastf, 0);
    if (!lastf) return;
    __threadfence();   // acquire: other blocks' ws writes now visible
    float s = 0.0f;
#pragma unroll
    for (int i = 0; i < 12; ++i) s += ws[2 + i];
    for (int b = lane; b < 4096; b += 64) {
        float v = s + LOG_SLOPE * ws[64 + b];
        if (isf32) ((float*)out)[524288 + b] = v;
        else ((unsigned short*)out)[524288 + b] = f2bf(v);
    }
}

extern "C" void kernel_launch(void* const* d_in, const int* in_sizes, int n_in,
                              void* d_out, int out_size, void* d_ws, size_t ws_size,
                              hipStream_t stream) {
    const void* x  = d_in[0];
    const void* W1 = d_in[1];
    const void* b1 = d_in[2];
    const void* W2 = d_in[3];
    const void* b2 = d_in[4];
    const void* W3 = d_in[5];
    const void* b3 = d_in[6];
    float* ws = (float*)d_ws;

    hipLaunchKernelGGL(k_prep, dim3(97), dim3(256), 0, stream,
                       W1, W2, W3, b1, b2, b3, ws);
    hipLaunchKernelGGL(k_main, dim3(NBLK), dim3(256), LDS_BYTES, stream,
                       x, W1, b1, W2, b2, W3, b3, d_out, ws);
}

// Round 5
// 248.403 us; speedup vs baseline: 1.0070x; 1.0070x over previous
//
#include <hip/hip_runtime.h>

typedef __attribute__((ext_vector_type(8))) short short8;
typedef __attribute__((ext_vector_type(4))) float float4f;
typedef __attribute__((ext_vector_type(4))) unsigned short ushort4v;

#define PITCH 136   // shorts/row in LDS planes
#define LOG_SLOPE -2.302585092994046f   // log(0.1)
#define LN2 0.6931471805599453f
#define NBLK 268    // 12 LU + 256 fwd (16 rows per fwd block, single wave)
#define LDS_BYTES 32256   // 6 planes * 16*136*2 + 1536 bias floats
// ws layout (floats): [0] ticket | [2..13] logdet partials | [64..4159] counts
// [4160..5695] fp32 biases | [8192..] W hi/lo ushort planes
#define WS_BIAS 4160
#define WS_WPLANES 8192
#define NWELEM 196608   // 12 * 16384

// Scheduling fence: bounds the pre-RA scheduler's hoisting window. Without it
// the SSA-renamed rolling reloads (s = loadTile(...)) all hoist to the top of
// matvec -> 8 tiles in flight -> 256+ VGPR -> scratch spill (r1-r4: 13-15MB
// scratch WRITE_SIZE, VGPR pegged). Fences cap in-flight at ~1 stage.
#define SB __builtin_amdgcn_sched_barrier(0)

__device__ __forceinline__ float bf2f(unsigned int u) {
    return __builtin_bit_cast(float, u << 16);
}
__device__ __forceinline__ unsigned short f2bf(float f) {
    unsigned int x = __builtin_bit_cast(unsigned int, f);
    x += 0x7fff + ((x >> 16) & 1);   // round-to-nearest-even
    return (unsigned short)(x >> 16);
}
__device__ __forceinline__ float4f vmsub(float4f a, float s, float4f b) {
    a[0] -= s * b[0]; a[1] -= s * b[1]; a[2] -= s * b[2]; a[3] -= s * b[3];
    return a;
}

template<int ISF32>
__device__ __forceinline__ float ldv(const void* p, int i) {
    if (ISF32) return ((const float*)p)[i];
    return bf2f(((const unsigned short*)p)[i]);
}

// Per-wave dtype sniff: fp32 weights read as u16 pairs have uniform-random
// mantissa halves; bf16 weights have exponent fields in a narrow band.
__device__ __forceinline__ int detect_f32(const unsigned short* W1u, int lane) {
    unsigned int u = W1u[lane * 2];
    unsigned int e = (u >> 7) & 0xFF;
    int bad = (e < 64) || (e > 135);
    return __ballot(bad) != 0ull;
}

__device__ __forceinline__ float4f mfma16(short8 a, short8 b, float4f c) {
    return __builtin_amdgcn_mfma_f32_16x16x32_bf16(a, b, c, 0, 0, 0);
}

__device__ __forceinline__ void split8(float4f a, float4f b, short8& hi, short8& lo) {
#pragma unroll
    for (int j = 0; j < 4; ++j) {
        float v = a[j]; unsigned short h = f2bf(v);
        hi[j] = (short)h; lo[j] = (short)f2bf(v - bf2f(h));
        v = b[j]; h = f2bf(v);
        hi[4 + j] = (short)h; lo[4 + j] = (short)f2bf(v - bf2f(h));
    }
}

// ---- prep: W -> bf16 hi/lo planes, biases -> fp32, zero ticket ----
__global__ void k_prep(const void* __restrict__ W1, const void* __restrict__ W2,
                       const void* __restrict__ W3, const void* __restrict__ b1,
                       const void* __restrict__ b2, const void* __restrict__ b3,
                       float* __restrict__ ws) {
    const int tid = threadIdx.x, bid = blockIdx.x;
    const int isf32 = detect_f32((const unsigned short*)W1, tid & 63);
    unsigned short* whi = (unsigned short*)(ws + WS_WPLANES);
    unsigned short* wlo = whi + NWELEM;
    if (bid < 96) {
        int s = (bid * 256 + tid) * 8;        // 96*256*8 = 196608
        int mat = s >> 14, off = s & 16383;   // mat = wsel*4 + layer
        int wsel = mat >> 2;
        const void* Wm = wsel == 0 ? W1 : (wsel == 1 ? W2 : W3);
        int src = (mat & 3) * 16384 + off;
        short8 hi, lo;
        if (isf32) {
            const float* p = (const float*)Wm + src;
            split8(*(const float4f*)p, *(const float4f*)(p + 4), hi, lo);
        } else {
            hi = *(const short8*)((const unsigned short*)Wm + src);
            lo = (short8){0, 0, 0, 0, 0, 0, 0, 0};
        }
        *(short8*)(whi + s) = hi;
        *(short8*)(wlo + s) = lo;
    } else {
        for (int e = tid; e < 1536; e += 256) {
            int bsel = e >> 9, idx = e & 511;
            const void* bp = bsel == 0 ? b1 : (bsel == 1 ? b2 : b3);
            ws[WS_BIAS + e] = isf32 ? ((const float*)bp)[idx]
                                    : bf2f(((const unsigned short*)bp)[idx]);
        }
        if (tid == 0) ((int*)ws)[0] = 0;   // finalize ticket
    }
}

// One 16-col weight tile as a VALUE struct (by-value aggregates promote to
// VGPRs). fp32: hi+lo interleaved (8 short8 = 32 VGPR); bf16: hi only
// (4 short8 = 16 VGPR, weight lo planes exactly zero -> bit-identical).
template<int ISF32> struct WT { short8 v[ISF32 ? 8 : 4]; };
struct XF { short8 h[4], l[4]; };

template<int ISF32>
__device__ __forceinline__ WT<ISF32> loadTile(const unsigned short* __restrict__ wh,
                                              const unsigned short* __restrict__ wl,
                                              int ct, int m, int q) {
    WT<ISF32> r;
    const unsigned short* ph = wh + (ct * 16 + m) * 128 + q * 8;
#pragma unroll
    for (int kk = 0; kk < 4; ++kk)
        r.v[kk * (ISF32 ? 2 : 1)] = *(const short8*)(ph + kk * 32);
    if (ISF32) {
        const unsigned short* pl = wl + (ct * 16 + m) * 128 + q * 8;
#pragma unroll
        for (int kk = 0; kk < 4; ++kk)
            r.v[kk * 2 + 1] = *(const short8*)(pl + kk * 32);
    }
    return r;
}

template<int ISF32>
__device__ __forceinline__ float4f dotTile(const WT<ISF32>& w, const XF& x, float4f acc) {
#pragma unroll
    for (int kk = 0; kk < 4; ++kk) {
        if (ISF32) {
            acc = mfma16(x.h[kk], w.v[kk * 2 + 0], acc);
            acc = mfma16(x.l[kk], w.v[kk * 2 + 0], acc);
            acc = mfma16(x.h[kk], w.v[kk * 2 + 1], acc);
        } else {
            acc = mfma16(x.h[kk], w.v[kk], acc);
            acc = mfma16(x.l[kk], w.v[kk], acc);
        }
    }
    return acc;
}

// Single-wave matvec: out[16x128] = f(in[16x128] @ W^T + bias). No barriers:
// same-wave LDS ordering suffices. s0/s1/s2 are rolling value-struct slots.
// Entry invariant: (s0,s1,s2) = tiles (0,1,2) of CURRENT matrix.
// Exit invariant:  (s0,s1,s2) = tiles (0,1,2) of NEXT matrix.
// SB fences pin the stage order at compile time; the hardware still overlaps:
// each reload issues ~2 dots (~400cy) before its consumer -> L2 latency hidden,
// but at most one stage of loads is ever in flight (spill-proof by construction).
// MODE 0: out=leaky(v) | 1: v+=res(LDS,=out plane), write | 2: leaky+count | 3: count only
template<int MODE, int ISF32>
__device__ __forceinline__ void matvec(
        WT<ISF32>& s0, WT<ISF32>& s1, WT<ISF32>& s2,
        const unsigned short* __restrict__ inh, const unsigned short* __restrict__ inl,
        unsigned short* outh, unsigned short* outl,
        const unsigned short* __restrict__ cwh, const unsigned short* __restrict__ cwl,
        const unsigned short* __restrict__ nwh, const unsigned short* __restrict__ nwl,
        const float* __restrict__ bias,
        int* cnt, int m, int q) {
    XF x;
#pragma unroll
    for (int kk = 0; kk < 4; ++kk) {
        x.h[kk] = *(const short8*)(inh + m * PITCH + kk * 32 + q * 8);
        x.l[kk] = *(const short8*)(inl + m * PITCH + kk * 32 + q * 8);
    }
    float4f a0, a1, a2, a3, a4, a5, a6, a7;
    {
        float b;
        b = bias[0 * 16 + m]; a0 = (float4f){b, b, b, b};
        b = bias[1 * 16 + m]; a1 = (float4f){b, b, b, b};
        b = bias[2 * 16 + m]; a2 = (float4f){b, b, b, b};
        b = bias[3 * 16 + m]; a3 = (float4f){b, b, b, b};
        b = bias[4 * 16 + m]; a4 = (float4f){b, b, b, b};
        b = bias[5 * 16 + m]; a5 = (float4f){b, b, b, b};
        b = bias[6 * 16 + m]; a6 = (float4f){b, b, b, b};
        b = bias[7 * 16 + m]; a7 = (float4f){b, b, b, b};
    }
    SB;
    a0 = dotTile<ISF32>(s0, x, a0); SB; s0 = loadTile<ISF32>(cwh, cwl, 3, m, q); SB;
    a1 = dotTile<ISF32>(s1, x, a1); SB; s1 = loadTile<ISF32>(cwh, cwl, 4, m, q); SB;
    a2 = dotTile<ISF32>(s2, x, a2); SB; s2 = loadTile<ISF32>(cwh, cwl, 5, m, q); SB;
    a3 = dotTile<ISF32>(s0, x, a3); SB; s0 = loadTile<ISF32>(cwh, cwl, 6, m, q); SB;
    a4 = dotTile<ISF32>(s1, x, a4); SB; s1 = loadTile<ISF32>(cwh, cwl, 7, m, q); SB;
    a5 = dotTile<ISF32>(s2, x, a5); SB; s2 = loadTile<ISF32>(nwh, nwl, 2, m, q); SB;
    a6 = dotTile<ISF32>(s0, x, a6); SB; s0 = loadTile<ISF32>(nwh, nwl, 0, m, q); SB;
    a7 = dotTile<ISF32>(s1, x, a7); SB; s1 = loadTile<ISF32>(nwh, nwl, 1, m, q); SB;

    // epilogue (C layout: row = q*4+r, col = ct*16+m), all indices literal
#define EPI_CT(A, CT)                                                          \
    {                                                                          \
        _Pragma("unroll")                                                      \
        for (int r = 0; r < 4; ++r) {                                          \
            float v = A[r];                                                    \
            const int o = (q * 4 + r) * PITCH + CT * 16 + m;                   \
            if (MODE == 1) v += bf2f(outh[o]) + bf2f(outl[o]);                 \
            if (MODE >= 2) cnt[r] += (v <= 0.0f) ? 1 : 0;                      \
            if (MODE == 0 || MODE == 2) v = v > 0.0f ? v : 0.1f * v;           \
            if (MODE != 3) {                                                   \
                unsigned short h = f2bf(v);                                    \
                outh[o] = h;                                                   \
                outl[o] = f2bf(v - bf2f(h));                                   \
            }                                                                  \
        }                                                                      \
    }
    EPI_CT(a0, 0) EPI_CT(a1, 1) EPI_CT(a2, 2) EPI_CT(a3, 3)
    EPI_CT(a4, 4) EPI_CT(a5, 5) EPI_CT(a6, 6) EPI_CT(a7, 7)
#undef EPI_CT
}

// Per-wave fwd: 16 rows through 4 layers x 5 matvecs, zero barriers.
// Planes: P0 = x/residual, P1/P2 = temporaries.
template<int ISF32>
__device__ void fwd(int bid, int lane, char* ldsb,
                    const void* __restrict__ x, const float* __restrict__ ws,
                    void* __restrict__ out, float* __restrict__ wsw) {
    unsigned short* P = (unsigned short*)ldsb;
    unsigned short* P0h = P + 0 * 16 * PITCH;
    unsigned short* P0l = P + 1 * 16 * PITCH;
    unsigned short* P1h = P + 2 * 16 * PITCH;
    unsigned short* P1l = P + 3 * 16 * PITCH;
    unsigned short* P2h = P + 4 * 16 * PITCH;
    unsigned short* P2l = P + 5 * 16 * PITCH;
    float* biasL = (float*)(ldsb + 6 * 16 * PITCH * 2);   // 1536 floats
    const unsigned short* whi = (const unsigned short*)(ws + WS_WPLANES);
    const unsigned short* wlo = whi + NWELEM;
    const float* biasG = ws + WS_BIAS;
    const int r0 = bid * 16;
    const int m = lane & 15, q = lane >> 4;

    // prologue: layer-0 w1 tiles 0..2 -> slots (loads fly while staging x + biases)
    WT<ISF32> s0 = loadTile<ISF32>(whi, wlo, 0, m, q);
    WT<ISF32> s1 = loadTile<ISF32>(whi, wlo, 1, m, q);
    WT<ISF32> s2 = loadTile<ISF32>(whi, wlo, 2, m, q);

    // stage biases -> LDS (read 8x per matvec as cheap ds_read_b32)
#pragma unroll
    for (int e = lane; e < 384; e += 64)
        *(float4f*)&biasL[e * 4] = *(const float4f*)&biasG[e * 4];

    // stage x -> P0 hi/lo (vectorized)
    if (ISF32) {
#pragma unroll
        for (int e = lane; e < 512; e += 64) {
            int r = e >> 5, c = (e & 31) * 4;
            float4f v = *(const float4f*)((const float*)x + (r0 + r) * 128 + c);
            ushort4v h, l;
#pragma unroll
            for (int j = 0; j < 4; ++j) {
                unsigned short hh = f2bf(v[j]);
                h[j] = hh; l[j] = f2bf(v[j] - bf2f(hh));
            }
            *(ushort4v*)(P0h + r * PITCH + c) = h;
            *(ushort4v*)(P0l + r * PITCH + c) = l;
        }
    } else {
        const short8 z = {0, 0, 0, 0, 0, 0, 0, 0};
#pragma unroll
        for (int e = lane; e < 256; e += 64) {
            int r = e >> 4, c = (e & 15) * 8;
            short8 v = *(const short8*)((const unsigned short*)x + (r0 + r) * 128 + c);
            *(short8*)(P0h + r * PITCH + c) = v;
            *(short8*)(P0l + r * PITCH + c) = z;
        }
    }
    int cnt[4] = {0, 0, 0, 0};
#pragma unroll 1
    for (int layer = 0; layer < 4; ++layer) {
        const unsigned short* w1h = whi + (0 + layer) * 16384;
        const unsigned short* w1l = wlo + (0 + layer) * 16384;
        const unsigned short* w2h = whi + (4 + layer) * 16384;
        const unsigned short* w2l = wlo + (4 + layer) * 16384;
        const unsigned short* w3h = whi + (8 + layer) * 16384;
        const unsigned short* w3l = wlo + (8 + layer) * 16384;
        const unsigned short* n1h = whi + ((layer + 1) & 3) * 16384;
        const unsigned short* n1l = wlo + ((layer + 1) & 3) * 16384;
        const float* b1p = biasL + layer * 128;
        const float* b2p = biasL + 512 + layer * 128;
        const float* b3p = biasL + 1024 + layer * 128;
        matvec<0, ISF32>(s0, s1, s2, P0h, P0l, P1h, P1l, w1h, w1l, w2h, w2l, b1p, cnt, m, q);
        matvec<0, ISF32>(s0, s1, s2, P1h, P1l, P2h, P2l, w2h, w2l, w3h, w3l, b2p, cnt, m, q);
        matvec<1, ISF32>(s0, s1, s2, P2h, P2l, P0h, P0l, w3h, w3l, w1h, w1l, b3p, cnt, m, q);
        matvec<2, ISF32>(s0, s1, s2, P0h, P0l, P1h, P1l, w1h, w1l, w2h, w2l, b1p, cnt, m, q);
        matvec<3, ISF32>(s0, s1, s2, P1h, P1l, P1h, P1l, w2h, w2l, n1h, n1l, b2p, cnt, m, q);
    }
    // count reduction across the 16-lane col groups (rows q*4+r)
#pragma unroll
    for (int r = 0; r < 4; ++r) {
        int c = cnt[r];
        c += __shfl_xor(c, 1);
        c += __shfl_xor(c, 2);
        c += __shfl_xor(c, 4);
        c += __shfl_xor(c, 8);
        if (m == 0) wsw[64 + r0 + q * 4 + r] = (float)c;
    }
    // final x from P0 hi/lo (vectorized)
    if (ISF32) {
#pragma unroll
        for (int e = lane; e < 512; e += 64) {
            int r = e >> 5, c = (e & 31) * 4;
            ushort4v h = *(const ushort4v*)(P0h + r * PITCH + c);
            ushort4v l = *(const ushort4v*)(P0l + r * PITCH + c);
            float4f v;
#pragma unroll
            for (int j = 0; j < 4; ++j) v[j] = bf2f(h[j]) + bf2f(l[j]);
            *(float4f*)((float*)out + (r0 + r) * 128 + c) = v;
        }
    } else {
#pragma unroll
        for (int e = lane; e < 256; e += 64) {
            int r = e >> 4, c = (e & 15) * 8;
            short8 h = *(const short8*)(P0h + r * PITCH + c);
            short8 l = *(const short8*)(P0l + r * PITCH + c);
            short8 o;
#pragma unroll
            for (int j = 0; j < 8; ++j)
                o[j] = (short)f2bf(bf2f((unsigned short)h[j]) + bf2f((unsigned short)l[j]));
            *(short8*)((unsigned short*)out + (r0 + r) * 128 + c) = o;
        }
    }
}

// ---- register-resident unpivoted LU, RANK-4 per barrier (32 intervals).
template<int ISF32>
__device__ __forceinline__ float lu_logdet(int id, int tid, float* lds,
        const void* W1, const void* W2, const void* W3) {
    const int wsel = id % 3;
    const void* Wm = (wsel == 0 ? W1 : (wsel == 1 ? W2 : W3));
    const int ofs = (id / 3) * 16384;
    const int tx = tid & 31, ty = tid >> 5;
    float* rowbuf = lds;          // [2][4][128]: rows K..K+3
    float* colbuf = lds + 1024;   // [2][4][128]: cols K..K+3 packed [j][ty*16+m]
    float4f V[16];                // A[ty+8m][4tx..4tx+3]
#pragma unroll
    for (int m = 0; m < 16; ++m) {
        int base = ofs + (ty + 8 * m) * 128 + 4 * tx;
        if (ISF32) {
            V[m] = *(const float4f*)((const float*)Wm + base);
        } else {
            ushort4 u = *(const ushort4*)((const unsigned short*)Wm + base);
            V[m] = (float4f){bf2f(u.x), bf2f(u.y), bf2f(u.z), bf2f(u.w)};
        }
    }
    if (ty < 4) *(float4f*)&rowbuf[ty * 128 + 4 * tx] = V[0];
    if (tx == 0) {
#pragma unroll
        for (int j = 0; j < 4; ++j) {
#pragma unroll
            for (int mg = 0; mg < 4; ++mg) {
                float4f t = {V[mg * 4 + 0][j], V[mg * 4 + 1][j],
                             V[mg * 4 + 2][j], V[mg * 4 + 3][j]};
                *(float4f*)&colbuf[j * 128 + ty * 16 + mg * 4] = t;
            }
        }
    }
    __syncthreads();
    float logacc = 0.0f;
#pragma unroll 1
    for (int kap = 0; kap < 32; ++kap) {
        const int K = kap * 4;
        const int buf = (kap & 1) * 512;
        float4f D[4], R[4], C[4][4];
#pragma unroll
        for (int j = 0; j < 4; ++j) {
            D[j] = *(const float4f*)&rowbuf[buf + j * 128 + K];       // broadcast
            R[j] = *(const float4f*)&rowbuf[buf + j * 128 + 4 * tx];
#pragma unroll
            for (int mg = 0; mg < 4; ++mg)
                C[j][mg] = *(const float4f*)&colbuf[buf + j * 128 + ty * 16 + mg * 4];
        }
        float p0 = D[0][0], i0 = 1.0f / p0;
        float l10 = D[1][0] * i0, l20 = D[2][0] * i0, l30 = D[3][0] * i0;
        D[1] = vmsub(D[1], l10, D[0]); R[1] = vmsub(R[1], l10, R[0]);
        D[2] = vmsub(D[2], l20, D[0]); R[2] = vmsub(R[2], l20, R[0]);
        D[3] = vmsub(D[3], l30, D[0]); R[3] = vmsub(R[3], l30, R[0]);
        float p1 = D[1][1], i1 = 1.0f / p1;
        float l21 = D[2][1] * i1, l31 = D[3][1] * i1;
        D[2] = vmsub(D[2], l21, D[1]); R[2] = vmsub(R[2], l21, R[1]);
        D[3] = vmsub(D[3], l31, D[1]); R[3] = vmsub(R[3], l31, R[1]);
        float p2 = D[2][2], i2 = 1.0f / p2;
        float l32 = D[3][2] * i2;
        D[3] = vmsub(D[3], l32, D[2]); R[3] = vmsub(R[3], l32, R[2]);
        float p3 = D[3][3], i3 = 1.0f / p3;
        logacc += __log2f(fabsf(p0)) + __log2f(fabsf(p1))
                + __log2f(fabsf(p2)) + __log2f(fabsf(p3));
        float iv[4] = {i0, i1, i2, i3};
#pragma unroll
        for (int i = 0; i < 4; ++i) {
#pragma unroll
            for (int mg = 0; mg < 4; ++mg) {
#pragma unroll
                for (int e = 0; e < 4; ++e) {
                    int r = ty + 32 * mg + 8 * e;
                    C[i][mg][e] = (r > K + i) ? C[i][mg][e] * iv[i] : 0.0f;
                }
            }
#pragma unroll
            for (int j = i + 1; j < 4; ++j) {
                float uij = D[i][j];
#pragma unroll
                for (int mg = 0; mg < 4; ++mg)
                    C[j][mg] = vmsub(C[j][mg], uij, C[i][mg]);
            }
        }
#pragma unroll
        for (int mg = 0; mg < 4; ++mg) {
#pragma unroll
            for (int e = 0; e < 4; ++e) {
                float4f v = V[mg * 4 + e];
                v = vmsub(v, C[0][mg][e], R[0]);
                v = vmsub(v, C[1][mg][e], R[1]);
                v = vmsub(v, C[2][mg][e], R[2]);
                v = vmsub(v, C[3][mg][e], R[3]);
                V[mg * 4 + e] = v;
            }
        }
        if (kap < 31) {
            const int nbuf = ((kap + 1) & 1) * 512;
            const int tb = (kap & 1) ? 0 : 4;
            const int mn = (kap + 1) >> 1;
            if (ty >= tb && ty < tb + 4) {
                float4f val;
                switch (mn) {
                case 0:  val = V[0];  break; case 1:  val = V[1];  break;
                case 2:  val = V[2];  break; case 3:  val = V[3];  break;
                case 4:  val = V[4];  break; case 5:  val = V[5];  break;
                case 6:  val = V[6];  break; case 7:  val = V[7];  break;
                case 8:  val = V[8];  break; case 9:  val = V[9];  break;
                case 10: val = V[10]; break; case 11: val = V[11]; break;
                case 12: val = V[12]; break; case 13: val = V[13]; break;
                case 14: val = V[14]; break; default: val = V[15]; break;
                }
                *(float4f*)&rowbuf[nbuf + (ty - tb) * 128 + 4 * tx] = val;
            }
            if (tx == kap + 1) {
#pragma unroll
                for (int j = 0; j < 4; ++j) {
#pragma unroll
                    for (int mg = 0; mg < 4; ++mg) {
                        float4f t = {V[mg * 4 + 0][j], V[mg * 4 + 1][j],
                                     V[mg * 4 + 2][j], V[mg * 4 + 3][j]};
                        *(float4f*)&colbuf[nbuf + j * 128 + ty * 16 + mg * 4] = t;
                    }
                }
            }
        }
        __syncthreads();
    }
    return logacc * LN2;
}

__global__ __launch_bounds__(256, 1) void k_main(
        const void* __restrict__ x,
        const void* __restrict__ W1, const void* __restrict__ b1,
        const void* __restrict__ W2, const void* __restrict__ b2,
        const void* __restrict__ W3, const void* __restrict__ b3,
        void* __restrict__ out, float* __restrict__ ws) {
    extern __shared__ __align__(16) char ldsb[];
    const int tid = threadIdx.x;
    const int lane = tid & 63;
    // fwd blocks: single active wave, waves 1-3 exit before any barrier
    if (blockIdx.x >= 12 && tid >= 64) return;
    const int isf32 = detect_f32((const unsigned short*)W1, lane);

    if (blockIdx.x < 12) {
        float ld = isf32 ? lu_logdet<1>(blockIdx.x, tid, (float*)ldsb, W1, W2, W3)
                         : lu_logdet<0>(blockIdx.x, tid, (float*)ldsb, W1, W2, W3);
        if (tid == 0) ws[2 + blockIdx.x] = ld;
        if (tid >= 64) return;   // only wave 0 continues (no more barriers)
    } else {
        const int bid = blockIdx.x - 12;
        if (isf32) fwd<1>(bid, lane, ldsb, x, ws, out, ws);
        else       fwd<0>(bid, lane, ldsb, x, ws, out, ws);
    }

    // ---- last-block finalize (wave 0 only, wave-level broadcast) ----
    __threadfence();
    int lastf = 0;
    if (lane == 0) lastf = (atomicAdd((int*)ws, 1) == NBLK - 1) ? 1 : 0;
    lastf = __shfl(lastf, 0);
    if (!lastf) return;
    __threadfence();   // acquire: other blocks' ws writes now visible
    float s = 0.0f;
#pragma unroll
    for (int i = 0; i < 12; ++i) s += ws[2 + i];
    for (int b = lane; b < 4096; b += 64) {
        float v = s + LOG_SLOPE * ws[64 + b];
        if (isf32) ((float*)out)[524288 + b] = v;
        else ((unsigned short*)out)[524288 + b] = f2bf(v);
    }
}

extern "C" void kernel_launch(void* const* d_in, const int* in_sizes, int n_in,
                              void* d_out, int out_size, void* d_ws, size_t ws_size,
                              hipStream_t stream) {
    const void* x  = d_in[0];
    const void* W1 = d_in[1];
    const void* b1 = d_in[2];
    const void* W2 = d_in[3];
    const void* b2 = d_in[4];
    const void* W3 = d_in[5];
    const void* b3 = d_in[6];
    float* ws = (float*)d_ws;

    hipLaunchKernelGGL(k_prep, dim3(97), dim3(256), 0, stream,
                       W1, W2, W3, b1, b2, b3, ws);
    hipLaunchKernelGGL(k_main, dim3(NBLK), dim3(256), LDS_BYTES, stream,
                       x, W1, b1, W2, b2, W3, b3, d_out, ws);
}

// Round 6
// 134.708 us; speedup vs baseline: 1.8569x; 1.8440x over previous
//
#include <hip/hip_runtime.h>

typedef __attribute__((ext_vector_type(8))) short short8;
typedef __attribute__((ext_vector_type(4))) float float4f;

#define PITCH 136   // shorts/row in LDS planes
#define ROWS 32     // rows per fwd block
#define LOG_SLOPE -2.302585092994046f   // log(0.1)
#define LN2 0.6931471805599453f
#define NBLK 140    // 12 LU + 128 fwd
#define LDS_BYTES 69760   // 8 planes * 32*136*2 + 128 cnt
// ws layout (floats): [0] ticket | [2..13] logdet partials | [64..4159] counts
// [4160..5695] fp32 biases | [8192..] W hi/lo ushort planes
#define WS_BIAS 4160
#define WS_WPLANES 8192
#define NWELEM 196608   // 12 * 16384

__device__ __forceinline__ float bf2f(unsigned int u) {
    return __builtin_bit_cast(float, u << 16);
}
__device__ __forceinline__ unsigned short f2bf(float f) {
    unsigned int x = __builtin_bit_cast(unsigned int, f);
    x += 0x7fff + ((x >> 16) & 1);   // round-to-nearest-even
    return (unsigned short)(x >> 16);
}
__device__ __forceinline__ float4f vmsub(float4f a, float s, float4f b) {
    a[0] -= s * b[0]; a[1] -= s * b[1]; a[2] -= s * b[2]; a[3] -= s * b[3];
    return a;
}
__device__ __forceinline__ float4f vscale(float4f a, float s) {
    a[0] *= s; a[1] *= s; a[2] *= s; a[3] *= s;
    return a;
}

template<int ISF32>
__device__ __forceinline__ float ldv(const void* p, int i) {
    if (ISF32) return ((const float*)p)[i];
    return bf2f(((const unsigned short*)p)[i]);
}

// Per-wave dtype sniff: fp32 weights read as u16 pairs have uniform-random
// mantissa halves; bf16 weights have exponent fields in a narrow band.
__device__ __forceinline__ int detect_f32(const unsigned short* W1u, int lane) {
    unsigned int u = W1u[lane * 2];
    unsigned int e = (u >> 7) & 0xFF;
    int bad = (e < 64) || (e > 135);
    return __ballot(bad) != 0ull;
}

__device__ __forceinline__ float4f mfma16(short8 a, short8 b, float4f c) {
    return __builtin_amdgcn_mfma_f32_16x16x32_bf16(a, b, c, 0, 0, 0);
}

__device__ __forceinline__ void split8(float4f a, float4f b, short8& hi, short8& lo) {
#pragma unroll
    for (int j = 0; j < 4; ++j) {
        float v = a[j]; unsigned short h = f2bf(v);
        hi[j] = (short)h; lo[j] = (short)f2bf(v - bf2f(h));
        v = b[j]; h = f2bf(v);
        hi[4 + j] = (short)h; lo[4 + j] = (short)f2bf(v - bf2f(h));
    }
}

// ---- prep: W -> bf16 hi/lo planes, biases -> fp32, zero ticket ----
__global__ void k_prep(const void* __restrict__ W1, const void* __restrict__ W2,
                       const void* __restrict__ W3, const void* __restrict__ b1,
                       const void* __restrict__ b2, const void* __restrict__ b3,
                       float* __restrict__ ws) {
    const int tid = threadIdx.x, bid = blockIdx.x;
    const int isf32 = detect_f32((const unsigned short*)W1, tid & 63);
    unsigned short* whi = (unsigned short*)(ws + WS_WPLANES);
    unsigned short* wlo = whi + NWELEM;
    if (bid < 96) {
        int s = (bid * 256 + tid) * 8;        // 96*256*8 = 196608
        int mat = s >> 14, off = s & 16383;   // mat = wsel*4 + layer
        int wsel = mat >> 2;
        const void* Wm = wsel == 0 ? W1 : (wsel == 1 ? W2 : W3);
        int src = (mat & 3) * 16384 + off;
        short8 hi, lo;
        if (isf32) {
            const float* p = (const float*)Wm + src;
            split8(*(const float4f*)p, *(const float4f*)(p + 4), hi, lo);
        } else {
            hi = *(const short8*)((const unsigned short*)Wm + src);
            lo = (short8){0, 0, 0, 0, 0, 0, 0, 0};
        }
        *(short8*)(whi + s) = hi;
        *(short8*)(wlo + s) = lo;
    } else {
        for (int e = tid; e < 1536; e += 256) {
            int bsel = e >> 9, idx = e & 511;
            const void* bp = bsel == 0 ? b1 : (bsel == 1 ? b2 : b3);
            ws[WS_BIAS + e] = isf32 ? ((const float*)bp)[idx]
                                    : bf2f(((const unsigned short*)bp)[idx]);
        }
        if (tid == 0) ((int*)ws)[0] = 0;   // finalize ticket
    }
}

// Weight fragment set for one matvec: [kk]{w0h,w1h,w0l,w1l}. All static indices.
struct W8 { short8 v[16]; };

__device__ __forceinline__ W8 loadW(const unsigned short* __restrict__ wh,
                                    const unsigned short* __restrict__ wl,
                                    int c0, int c1, int q) {
    W8 r;
#pragma unroll
    for (int kk = 0; kk < 4; ++kk) {
        const int kc = kk * 32 + q * 8;
        r.v[kk * 4 + 0] = *(const short8*)(wh + c0 * 128 + kc);
        r.v[kk * 4 + 1] = *(const short8*)(wh + c1 * 128 + kc);
        r.v[kk * 4 + 2] = *(const short8*)(wl + c0 * 128 + kc);
        r.v[kk * 4 + 3] = *(const short8*)(wl + c1 * 128 + kc);
    }
    return r;
}

// out[ROWS x 128] = act( in[ROWS x 128] @ W^T + bias ); ping-pong planes,
// one barrier per matvec. Weights for THIS matvec arrive preloaded in `w`;
// the NEXT matvec's weights are prefetched right after the barrier so their
// L2 latency hides behind this matvec's MFMAs + epilogue.
// MODE 0: out = leaky(v) | 1: out = res + v | 2: out = leaky(v)+count | 3: count only
template<int MODE>
__device__ __forceinline__ W8 matvec(const W8& w,
        const unsigned short* inh, const unsigned short* inl,
        unsigned short* outh, unsigned short* outl,
        const unsigned short* resh, const unsigned short* resl,
        const unsigned short* __restrict__ nwh, const unsigned short* __restrict__ nwl,
        const float* __restrict__ bias,
        int lane, int colb, int* cnt) {
    const int m = lane & 15, q = lane >> 4;
    const int c0 = colb + m, c1 = colb + 16 + m;
    float b0 = bias[c0], b1v = bias[c1];
    float4f acc[2][2];
#pragma unroll
    for (int rt = 0; rt < 2; ++rt) {
        acc[rt][0] = (float4f){b0, b0, b0, b0};
        acc[rt][1] = (float4f){b1v, b1v, b1v, b1v};
    }
    __syncthreads();   // previous matvec's LDS writes visible; w's loads drained
    W8 wn = loadW(nwh, nwl, c0, c1, q);   // prefetch next matvec's weights
#pragma unroll
    for (int kk = 0; kk < 4; ++kk) {
        const int kc = kk * 32 + q * 8;
#pragma unroll
        for (int rt = 0; rt < 2; ++rt) {
            short8 xh = *(const short8*)(inh + (rt * 16 + m) * PITCH + kc);
            short8 xl = *(const short8*)(inl + (rt * 16 + m) * PITCH + kc);
            acc[rt][0] = mfma16(xh, w.v[kk * 4 + 0], acc[rt][0]);
            acc[rt][0] = mfma16(xl, w.v[kk * 4 + 0], acc[rt][0]);
            acc[rt][0] = mfma16(xh, w.v[kk * 4 + 2], acc[rt][0]);
            acc[rt][1] = mfma16(xh, w.v[kk * 4 + 1], acc[rt][1]);
            acc[rt][1] = mfma16(xl, w.v[kk * 4 + 1], acc[rt][1]);
            acc[rt][1] = mfma16(xh, w.v[kk * 4 + 3], acc[rt][1]);
        }
    }
    int c[2][4];
#pragma unroll
    for (int rt = 0; rt < 2; ++rt) {
#pragma unroll
        for (int r = 0; r < 4; ++r) {
            float v0 = acc[rt][0][r], v1 = acc[rt][1][r];
            int row = rt * 16 + q * 4 + r;
            int o0 = row * PITCH + c0, o1 = row * PITCH + c1;
            if (MODE == 1) {
                v0 += bf2f(resh[o0]) + bf2f(resl[o0]);
                v1 += bf2f(resh[o1]) + bf2f(resl[o1]);
            }
            if (MODE >= 2) c[rt][r] = (v0 <= 0.0f) + (v1 <= 0.0f);
            if (MODE == 0 || MODE == 2) {
                v0 = v0 > 0.0f ? v0 : 0.1f * v0;
                v1 = v1 > 0.0f ? v1 : 0.1f * v1;
            }
            if (MODE != 3) {
                unsigned short h0 = f2bf(v0);
                outh[o0] = h0; outl[o0] = f2bf(v0 - bf2f(h0));
                unsigned short h1 = f2bf(v1);
                outh[o1] = h1; outl[o1] = f2bf(v1 - bf2f(h1));
            }
        }
    }
    if (MODE >= 2) {
#pragma unroll
        for (int rt = 0; rt < 2; ++rt) {
#pragma unroll
            for (int r = 0; r < 4; ++r) {
                int cc = c[rt][r];
                cc += __shfl_xor(cc, 1);
                cc += __shfl_xor(cc, 2);
                cc += __shfl_xor(cc, 4);
                cc += __shfl_xor(cc, 8);
                if (m == 0) atomicAdd(&cnt[rt * 16 + q * 4 + r], cc);
            }
        }
    }
    return wn;
}

template<int ISF32>
__device__ __forceinline__ void fwd(int bid, int tid, int lane, char* ldsb,
                                    const void* x, const float* ws, void* out,
                                    float* wsw) {
    unsigned short* P = (unsigned short*)ldsb;
    unsigned short* Ah = P;
    unsigned short* Al = P + 1 * ROWS * PITCH;
    unsigned short* Bh = P + 2 * ROWS * PITCH;
    unsigned short* Bl = P + 3 * ROWS * PITCH;
    unsigned short* Th = P + 4 * ROWS * PITCH;
    unsigned short* Tl = P + 5 * ROWS * PITCH;
    unsigned short* Uh = P + 6 * ROWS * PITCH;
    unsigned short* Ul = P + 7 * ROWS * PITCH;
    int* cnt = (int*)(P + 8 * ROWS * PITCH);
    const unsigned short* whi = (const unsigned short*)(ws + WS_WPLANES);
    const unsigned short* wlo = whi + NWELEM;
    const float* bias = ws + WS_BIAS;
    const int r0 = bid * ROWS;
    const int m = lane & 15, q = lane >> 4;
    const int colb = (tid >> 6) * 32;
    const int c0 = colb + m, c1 = colb + 16 + m;
    // prefetch layer-0 w1 while staging x into LDS
    W8 wcur = loadW(whi, wlo, c0, c1, q);
    for (int e = tid; e < ROWS * 128; e += 256) {
        int r = e >> 7, c = e & 127;
        float v = ldv<ISF32>(x, (r0 + r) * 128 + c);
        unsigned short h = f2bf(v);
        Ah[r * PITCH + c] = h;
        Al[r * PITCH + c] = f2bf(v - bf2f(h));
    }
    if (tid < ROWS) cnt[tid] = 0;
    unsigned short *curh = Ah, *curl = Al, *othh = Bh, *othl = Bl;
#pragma unroll 1
    for (int layer = 0; layer < 4; ++layer) {
        const unsigned short* w1h = whi + (0 + layer) * 16384;
        const unsigned short* w1l = wlo + (0 + layer) * 16384;
        const unsigned short* w2h = whi + (4 + layer) * 16384;
        const unsigned short* w2l = wlo + (4 + layer) * 16384;
        const unsigned short* w3h = whi + (8 + layer) * 16384;
        const unsigned short* w3l = wlo + (8 + layer) * 16384;
        const unsigned short* n1h = whi + ((layer + 1) & 3) * 16384;  // next-layer w1
        const unsigned short* n1l = wlo + ((layer + 1) & 3) * 16384;
        const float* b1p = bias + layer * 128;
        const float* b2p = bias + 512 + layer * 128;
        const float* b3p = bias + 1024 + layer * 128;
        wcur = matvec<0>(wcur, curh, curl, Th, Tl, 0, 0, w2h, w2l, b1p, lane, colb, cnt);
        wcur = matvec<0>(wcur, Th, Tl, Uh, Ul, 0, 0, w3h, w3l, b2p, lane, colb, cnt);
        wcur = matvec<1>(wcur, Uh, Ul, othh, othl, curh, curl, w1h, w1l, b3p, lane, colb, cnt);
        wcur = matvec<2>(wcur, othh, othl, Th, Tl, 0, 0, w2h, w2l, b1p, lane, colb, cnt);
        wcur = matvec<3>(wcur, Th, Tl, Th, Tl, 0, 0, n1h, n1l, b2p, lane, colb, cnt);
        unsigned short* t;
        t = curh; curh = othh; othh = t;
        t = curl; curl = othl; othl = t;
    }
    __syncthreads();
    for (int e = tid; e < ROWS * 128; e += 256) {
        int r = e >> 7, c = e & 127;
        float v = bf2f(curh[r * PITCH + c]) + bf2f(curl[r * PITCH + c]);
        if (ISF32) ((float*)out)[(r0 + r) * 128 + c] = v;
        else ((unsigned short*)out)[(r0 + r) * 128 + c] = f2bf(v);
    }
    if (tid < ROWS) wsw[64 + r0 + tid] = (float)cnt[tid];
}

// ---- register-resident unpivoted LU, RANK-4 per barrier (32 intervals).
// r6 change: trailing update uses V -= C_raw * (Upanel^{-1} R) instead of
// masked multipliers + within-panel propagation. Identity: L_block =
// C_raw * Upanel^{-1}, so L_block*R = C_raw*(Upanel^{-1}*R); the 4-step
// back-substitution (10 f4-ops) replaces ~56 f4-ops of masking+propagation.
// Unmasked updates corrupt only dead rows (r <= K+3), which are never staged
// or read again; logdet reads only the panel diagonal.
template<int ISF32>
__device__ __forceinline__ float lu_logdet(int id, int tid, float* lds,
        const void* W1, const void* W2, const void* W3) {
    const int wsel = id % 3;
    const void* Wm = (wsel == 0 ? W1 : (wsel == 1 ? W2 : W3));
    const int ofs = (id / 3) * 16384;
    const int tx = tid & 31, ty = tid >> 5;
    float* rowbuf = lds;          // [2][4][128]: rows K..K+3
    float* colbuf = lds + 1024;   // [2][4][128]: cols K..K+3 packed [j][ty*16+m]
    float4f V[16];                // A[ty+8m][4tx..4tx+3]
#pragma unroll
    for (int m = 0; m < 16; ++m) {
        int base = ofs + (ty + 8 * m) * 128 + 4 * tx;
        if (ISF32) {
            V[m] = *(const float4f*)((const float*)Wm + base);
        } else {
            ushort4 u = *(const ushort4*)((const unsigned short*)Wm + base);
            V[m] = (float4f){bf2f(u.x), bf2f(u.y), bf2f(u.z), bf2f(u.w)};
        }
    }
    // stage interval 0: rows 0..3 (ty 0..3, all m=0), cols 0..3 (owner tx==0)
    if (ty < 4) *(float4f*)&rowbuf[ty * 128 + 4 * tx] = V[0];
    if (tx == 0) {
#pragma unroll
        for (int j = 0; j < 4; ++j) {
#pragma unroll
            for (int mg = 0; mg < 4; ++mg) {
                float4f t = {V[mg * 4 + 0][j], V[mg * 4 + 1][j],
                             V[mg * 4 + 2][j], V[mg * 4 + 3][j]};
                *(float4f*)&colbuf[j * 128 + ty * 16 + mg * 4] = t;
            }
        }
    }
    __syncthreads();
    float logacc = 0.0f;
#pragma unroll 1
    for (int kap = 0; kap < 32; ++kap) {
        const int K = kap * 4;
        const int buf = (kap & 1) * 512;
        float4f D[4], R[4], C[4][4];
#pragma unroll
        for (int j = 0; j < 4; ++j) {
            D[j] = *(const float4f*)&rowbuf[buf + j * 128 + K];       // broadcast
            R[j] = *(const float4f*)&rowbuf[buf + j * 128 + 4 * tx];
#pragma unroll
            for (int mg = 0; mg < 4; ++mg)
                C[j][mg] = *(const float4f*)&colbuf[buf + j * 128 + ty * 16 + mg * 4];
        }
        // 4x4 panel factorization, redundant per thread
        float p0 = D[0][0], i0 = 1.0f / p0;
        float l10 = D[1][0] * i0, l20 = D[2][0] * i0, l30 = D[3][0] * i0;
        D[1] = vmsub(D[1], l10, D[0]); R[1] = vmsub(R[1], l10, R[0]);
        D[2] = vmsub(D[2], l20, D[0]); R[2] = vmsub(R[2], l20, R[0]);
        D[3] = vmsub(D[3], l30, D[0]); R[3] = vmsub(R[3], l30, R[0]);
        float p1 = D[1][1], i1 = 1.0f / p1;
        float l21 = D[2][1] * i1, l31 = D[3][1] * i1;
        D[2] = vmsub(D[2], l21, D[1]); R[2] = vmsub(R[2], l21, R[1]);
        D[3] = vmsub(D[3], l31, D[1]); R[3] = vmsub(R[3], l31, R[1]);
        float p2 = D[2][2], i2 = 1.0f / p2;
        float l32 = D[3][2] * i2;
        D[3] = vmsub(D[3], l32, D[2]); R[3] = vmsub(R[3], l32, R[2]);
        float p3 = D[3][3], i3 = 1.0f / p3;
        logacc += __log2f(fabsf(p0)) + __log2f(fabsf(p1))
                + __log2f(fabsf(p2)) + __log2f(fabsf(p3));
        // back-substitution: X = Upanel^{-1} * R  (solve U X = R, U upper-tri)
        float4f X3 = vscale(R[3], i3);
        float4f X2 = vscale(vmsub(R[2], D[2][3], X3), i2);
        float4f X1 = vscale(vmsub(vmsub(R[1], D[1][2], X2), D[1][3], X3), i1);
        float4f X0 = vscale(vmsub(vmsub(vmsub(R[0], D[0][1], X1),
                                        D[0][2], X2), D[0][3], X3), i0);
        // rank-4 trailing update with RAW column values (no masking needed)
#pragma unroll
        for (int mg = 0; mg < 4; ++mg) {
#pragma unroll
            for (int e = 0; e < 4; ++e) {
                float4f v = V[mg * 4 + e];
                v = vmsub(v, C[0][mg][e], X0);
                v = vmsub(v, C[1][mg][e], X1);
                v = vmsub(v, C[2][mg][e], X2);
                v = vmsub(v, C[3][mg][e], X3);
                V[mg * 4 + e] = v;
            }
        }
        // stage next interval (rows/cols K+4..K+7)
        if (kap < 31) {
            const int nbuf = ((kap + 1) & 1) * 512;
            const int tb = (kap & 1) ? 0 : 4;     // rows K+4..K+7 -> ty in [tb,tb+4)
            const int mn = (kap + 1) >> 1;        // their m index (uniform)
            if (ty >= tb && ty < tb + 4) {
                float4f val;
                switch (mn) {                     // uniform switch, static reg index
                case 0:  val = V[0];  break; case 1:  val = V[1];  break;
                case 2:  val = V[2];  break; case 3:  val = V[3];  break;
                case 4:  val = V[4];  break; case 5:  val = V[5];  break;
                case 6:  val = V[6];  break; case 7:  val = V[7];  break;
                case 8:  val = V[8];  break; case 9:  val = V[9];  break;
                case 10: val = V[10]; break; case 11: val = V[11]; break;
                case 12: val = V[12]; break; case 13: val = V[13]; break;
                case 14: val = V[14]; break; default: val = V[15]; break;
                }
                *(float4f*)&rowbuf[nbuf + (ty - tb) * 128 + 4 * tx] = val;
            }
            if (tx == kap + 1) {   // owner of cols K+4..K+7 (4-aligned)
#pragma unroll
                for (int j = 0; j < 4; ++j) {
#pragma unroll
                    for (int mg = 0; mg < 4; ++mg) {
                        float4f t = {V[mg * 4 + 0][j], V[mg * 4 + 1][j],
                                     V[mg * 4 + 2][j], V[mg * 4 + 3][j]};
                        *(float4f*)&colbuf[nbuf + j * 128 + ty * 16 + mg * 4] = t;
                    }
                }
            }
        }
        __syncthreads();   // one barrier per 4 pivots
    }
    return logacc * LN2;
}

__global__ __launch_bounds__(256) void k_main(
        const void* __restrict__ x,
        const void* __restrict__ W1, const void* __restrict__ b1,
        const void* __restrict__ W2, const void* __restrict__ b2,
        const void* __restrict__ W3, const void* __restrict__ b3,
        void* __restrict__ out, float* __restrict__ ws) {
    extern __shared__ __align__(16) char ldsb[];
    __shared__ int s_last;
    const int tid = threadIdx.x;
    const int lane = tid & 63;
    const int isf32 = detect_f32((const unsigned short*)W1, lane);

    if (blockIdx.x < 12) {
        float ld = isf32 ? lu_logdet<1>(blockIdx.x, tid, (float*)ldsb, W1, W2, W3)
                         : lu_logdet<0>(blockIdx.x, tid, (float*)ldsb, W1, W2, W3);
        if (tid == 0) ws[2 + blockIdx.x] = ld;
    } else {
        const int bid = blockIdx.x - 12;
        if (isf32) fwd<1>(bid, tid, lane, ldsb, x, ws, out, ws);
        else       fwd<0>(bid, tid, lane, ldsb, x, ws, out, ws);
    }

    // ---- last-block finalize ----
    __threadfence();
    if (tid == 0) s_last = (atomicAdd((int*)ws, 1) == NBLK - 1);
    __syncthreads();
    if (!s_last) return;
    __threadfence();   // acquire: other blocks' ws writes now visible
    float s = 0.0f;
#pragma unroll
    for (int i = 0; i < 12; ++i) s += ws[2 + i];
    for (int b = tid; b < 4096; b += 256) {
        float v = s + LOG_SLOPE * ws[64 + b];
        if (isf32) ((float*)out)[524288 + b] = v;
        else ((unsigned short*)out)[524288 + b] = f2bf(v);
    }
}

extern "C" void kernel_launch(void* const* d_in, const int* in_sizes, int n_in,
                              void* d_out, int out_size, void* d_ws, size_t ws_size,
                              hipStream_t stream) {
    const void* x  = d_in[0];
    const void* W1 = d_in[1];
    const void* b1 = d_in[2];
    const void* W2 = d_in[3];
    const void* b2 = d_in[4];
    const void* W3 = d_in[5];
    const void* b3 = d_in[6];
    float* ws = (float*)d_ws;

    hipLaunchKernelGGL(k_prep, dim3(97), dim3(256), 0, stream,
                       W1, W2, W3, b1, b2, b3, ws);
    hipLaunchKernelGGL(k_main, dim3(NBLK), dim3(256), LDS_BYTES, stream,
                       x, W1, b1, W2, b2, W3, b3, d_out, ws);
}